// Round 1
// baseline (997.704 us; speedup 1.0000x reference)
//
#include <hip/hip_runtime.h>

#define BATCH 32
#define T_LEN 4096
#define NU 64
#define NX 128
#define NY 64
#define KCH 64
#define NC (T_LEN / KCH)   /* 64 chunks */

/* workspace float offsets */
#define OFF_E   0
#define OFF_F   16384
#define OFF_A   32768
#define OFF_P0  49152
#define OFF_P1  65536
#define OFF_L   81920                 /* NC*BATCH*NX = 262144 floats */
#define OFF_XC  (81920 + 262144)     /* NC*BATCH*NX = 262144 floats */

/* ---- K1: E = 0.5*(S22+S11)+1e-9 I, F = S21, from M (256x256) ---- */
__global__ void ef_kernel(const float* __restrict__ M, float* __restrict__ E,
                          float* __restrict__ F) {
    int i = blockIdx.x;      // row 0..127
    int j = threadIdx.x;     // col 0..127
    const float* Mi2 = M + (size_t)(128 + i) * 256;
    const float* Mj1 = M + (size_t)j * 256;
    if (blockIdx.y == 0) {
        const float* Mi1 = M + (size_t)i * 256;
        const float* Mj2 = M + (size_t)(128 + j) * 256;
        float s11 = 0.f, s22 = 0.f;
        for (int m = 0; m < 256; ++m) {
            s11 += Mi1[m] * Mj1[m];
            s22 += Mi2[m] * Mj2[m];
        }
        float e = 0.5f * (s11 + s22);
        if (i == j) e += 1e-9f;
        E[i * NX + j] = e;
    } else {
        float s21 = 0.f;
        for (int m = 0; m < 256; ++m) s21 += Mi2[m] * Mj1[m];
        F[i * NX + j] = s21;
    }
}

/* ---- K2: solve E * A = F by Gaussian elimination (E SPD, no pivoting) ---- */
__global__ __launch_bounds__(256) void solve_kernel(const float* __restrict__ E,
                                                    const float* __restrict__ F,
                                                    float* __restrict__ A) {
    __shared__ float aug[NX][2 * NX + 2];   // cols 0..127 = E, 128..255 = F->A
    int tid = threadIdx.x;
    for (int idx = tid; idx < NX * NX; idx += 256) {
        int i = idx >> 7, j = idx & 127;
        aug[i][j] = E[idx];
        aug[i][NX + j] = F[idx];
    }
    /* forward elimination */
    for (int k = 0; k < NX; ++k) {
        __syncthreads();
        float invp = 1.0f / aug[k][k];
        for (int i = k + 1 + (tid >> 1); i < NX; i += 128) {
            float m = aug[i][k] * invp;
            for (int j = k + 1 + (tid & 1); j < 2 * NX; j += 2)
                aug[i][j] -= m * aug[k][j];
        }
    }
    /* back substitution: rows high->low, result into cols 128..255 */
    for (int k = NX - 1; k >= 0; --k) {
        __syncthreads();
        if (tid < NX) {
            float invp = 1.0f / aug[k][k];
            float s = aug[k][NX + tid];
            for (int i = k + 1; i < NX; ++i) s -= aug[k][i] * aug[i][NX + tid];
            aug[k][NX + tid] = s * invp;
        }
    }
    __syncthreads();
    for (int idx = tid; idx < NX * NX; idx += 256)
        A[idx] = aug[idx >> 7][NX + (idx & 127)];
}

/* ---- K3: Z = X*Y, 128x128 fp32 ---- */
__global__ void matmul128_kernel(const float* __restrict__ X,
                                 const float* __restrict__ Y,
                                 float* __restrict__ Z) {
    int i = blockIdx.x, j = threadIdx.x;
    float a0 = 0.f, a1 = 0.f, a2 = 0.f, a3 = 0.f;
    for (int m = 0; m < NX; m += 4) {
        a0 += X[i * NX + m]     * Y[(m)     * NX + j];
        a1 += X[i * NX + m + 1] * Y[(m + 1) * NX + j];
        a2 += X[i * NX + m + 2] * Y[(m + 2) * NX + j];
        a3 += X[i * NX + m + 3] * Y[(m + 3) * NX + j];
    }
    Z[i * NX + j] = (a0 + a1) + (a2 + a3);
}

/* ---- K4: phase 1 — local chunk scans from zero state; writes L[c][b][:] ---- */
__global__ __launch_bounds__(256) void phase1_kernel(const float* __restrict__ u_,
                                                     const float* __restrict__ A,
                                                     const float* __restrict__ Bm,
                                                     float* __restrict__ L) {
    __shared__ float As[NX][NX + 1];
    __shared__ float zs[2][NX];
    __shared__ float us[2][NU];
    int tid = threadIdx.x;
    int p = tid >> 7, i = tid & 127;
    int pair0 = blockIdx.x * 2;
    int pair = pair0 + p;           // pair = c*BATCH + b
    int c = pair >> 5, b = pair & 31;
    for (int idx = tid; idx < NX * NX; idx += 256)
        As[idx >> 7][idx & 127] = A[idx];
    float Br[NU];
#pragma unroll
    for (int j = 0; j < NU; ++j) Br[j] = Bm[i * NU + j];
    zs[p][i] = 0.f;
    __syncthreads();
    (void)c; (void)b;
    float zn = 0.f;
    for (int m = 0; m < KCH; ++m) {
        if (tid < 2 * NU) {
            int pp = tid >> 6, jj = tid & 63;
            int pr = pair0 + pp;
            int bb = pr & 31, cc = pr >> 5;
            us[pp][jj] = u_[((size_t)bb * T_LEN + (size_t)cc * KCH + m) * NU + jj];
        }
        __syncthreads();
        float a0 = 0.f, a1 = 0.f, a2 = 0.f, a3 = 0.f;
        for (int j = 0; j < NX; j += 4) {
            a0 += As[i][j]     * zs[p][j];
            a1 += As[i][j + 1] * zs[p][j + 1];
            a2 += As[i][j + 2] * zs[p][j + 2];
            a3 += As[i][j + 3] * zs[p][j + 3];
        }
#pragma unroll
        for (int j = 0; j < NU; j += 4) {
            a0 += Br[j]     * us[p][j];
            a1 += Br[j + 1] * us[p][j + 1];
            a2 += Br[j + 2] * us[p][j + 2];
            a3 += Br[j + 3] * us[p][j + 3];
        }
        zn = (a0 + a1) + (a2 + a3);
        __syncthreads();
        zs[p][i] = zn;
    }
    L[(size_t)pair * NX + i] = zn;
}

/* ---- K5: phase 2 — chunk-level recurrence Xc[c+1] = A^K Xc[c] + L[c] ---- */
__global__ __launch_bounds__(128) void phase2_kernel(const float* __restrict__ AK,
                                                     const float* __restrict__ L,
                                                     const float* __restrict__ x0,
                                                     float* __restrict__ Xc) {
    __shared__ float Ks[NX][NX + 1];
    __shared__ float xs[NX];
    int tid = threadIdx.x, b = blockIdx.x;
    for (int idx = tid; idx < NX * NX; idx += 128)
        Ks[idx >> 7][idx & 127] = AK[idx];
    float x = x0[tid];
    xs[tid] = x;
    Xc[(size_t)(0 * BATCH + b) * NX + tid] = x;
    __syncthreads();
    for (int c = 0; c < NC - 1; ++c) {
        float a0 = 0.f, a1 = 0.f, a2 = 0.f, a3 = 0.f;
        for (int j = 0; j < NX; j += 4) {
            a0 += Ks[tid][j]     * xs[j];
            a1 += Ks[tid][j + 1] * xs[j + 1];
            a2 += Ks[tid][j + 2] * xs[j + 2];
            a3 += Ks[tid][j + 3] * xs[j + 3];
        }
        float xn = (a0 + a1) + (a2 + a3) + L[((size_t)c * BATCH + b) * NX + tid];
        __syncthreads();
        xs[tid] = xn;
        Xc[((size_t)(c + 1) * BATCH + b) * NX + tid] = xn;
        __syncthreads();
    }
}

/* ---- K6: phase 3 — re-run chunks from true start state, emit y = C x ---- */
__global__ __launch_bounds__(256) void phase3_kernel(const float* __restrict__ u_,
                                                     const float* __restrict__ A,
                                                     const float* __restrict__ Bm,
                                                     const float* __restrict__ C,
                                                     const float* __restrict__ Xc,
                                                     float* __restrict__ y) {
    __shared__ float As[NX][NX + 1];
    __shared__ float xs[2][NX];
    __shared__ float us[2][NU];
    int tid = threadIdx.x;
    int p = tid >> 7, i = tid & 127;
    int q = tid & 127, r = q >> 1, h = q & 1;   // y roles: row r, half h
    int pair0 = blockIdx.x * 2;
    int pair = pair0 + p;
    int c = pair >> 5, b = pair & 31;
    for (int idx = tid; idx < NX * NX; idx += 256)
        As[idx >> 7][idx & 127] = A[idx];
    float Br[NU];
#pragma unroll
    for (int j = 0; j < NU; ++j) Br[j] = Bm[i * NU + j];
    float Cr[NU];
#pragma unroll
    for (int j = 0; j < NU; ++j) Cr[j] = C[r * NX + h * NU + j];
    xs[p][i] = Xc[(size_t)pair * NX + i];
    __syncthreads();
    /* emit k = 0 */
    {
        float a0 = 0.f, a1 = 0.f, a2 = 0.f, a3 = 0.f;
#pragma unroll
        for (int j = 0; j < NU; j += 4) {
            a0 += Cr[j]     * xs[p][h * NU + j];
            a1 += Cr[j + 1] * xs[p][h * NU + j + 1];
            a2 += Cr[j + 2] * xs[p][h * NU + j + 2];
            a3 += Cr[j + 3] * xs[p][h * NU + j + 3];
        }
        float s = (a0 + a1) + (a2 + a3);
        s += __shfl_xor(s, 1);
        if (h == 0)
            y[((size_t)b * T_LEN + (size_t)c * KCH + 0) * NY + r] = s;
    }
    for (int k = 1; k < KCH; ++k) {
        if (tid < 2 * NU) {
            int pp = tid >> 6, jj = tid & 63;
            int pr = pair0 + pp;
            int bb = pr & 31, cc = pr >> 5;
            us[pp][jj] = u_[((size_t)bb * T_LEN + (size_t)cc * KCH + k - 1) * NU + jj];
        }
        __syncthreads();
        float a0 = 0.f, a1 = 0.f, a2 = 0.f, a3 = 0.f;
        for (int j = 0; j < NX; j += 4) {
            a0 += As[i][j]     * xs[p][j];
            a1 += As[i][j + 1] * xs[p][j + 1];
            a2 += As[i][j + 2] * xs[p][j + 2];
            a3 += As[i][j + 3] * xs[p][j + 3];
        }
#pragma unroll
        for (int j = 0; j < NU; j += 4) {
            a0 += Br[j]     * us[p][j];
            a1 += Br[j + 1] * us[p][j + 1];
            a2 += Br[j + 2] * us[p][j + 2];
            a3 += Br[j + 3] * us[p][j + 3];
        }
        float xn = (a0 + a1) + (a2 + a3);
        __syncthreads();
        xs[p][i] = xn;
        __syncthreads();
        /* emit k */
        float c0 = 0.f, c1 = 0.f, c2 = 0.f, c3 = 0.f;
#pragma unroll
        for (int j = 0; j < NU; j += 4) {
            c0 += Cr[j]     * xs[p][h * NU + j];
            c1 += Cr[j + 1] * xs[p][h * NU + j + 1];
            c2 += Cr[j + 2] * xs[p][h * NU + j + 2];
            c3 += Cr[j + 3] * xs[p][h * NU + j + 3];
        }
        float s = (c0 + c1) + (c2 + c3);
        s += __shfl_xor(s, 1);
        if (h == 0)
            y[((size_t)b * T_LEN + (size_t)c * KCH + k) * NY + r] = s;
    }
}

extern "C" void kernel_launch(void* const* d_in, const int* in_sizes, int n_in,
                              void* d_out, int out_size, void* d_ws, size_t ws_size,
                              hipStream_t stream) {
    const float* u_  = (const float*)d_in[0];
    const float* M   = (const float*)d_in[1];
    const float* Bm  = (const float*)d_in[2];
    const float* C   = (const float*)d_in[3];
    const float* x0  = (const float*)d_in[4];
    float* y = (float*)d_out;
    float* ws = (float*)d_ws;

    float* E  = ws + OFF_E;
    float* F  = ws + OFF_F;
    float* A  = ws + OFF_A;
    float* P0 = ws + OFF_P0;
    float* P1 = ws + OFF_P1;
    float* L  = ws + OFF_L;
    float* Xc = ws + OFF_XC;

    ef_kernel<<<dim3(128, 2), 128, 0, stream>>>(M, E, F);
    solve_kernel<<<1, 256, 0, stream>>>(E, F, A);
    /* A^64 by repeated squaring: A2,A4,A8,A16,A32,A64 */
    matmul128_kernel<<<128, 128, 0, stream>>>(A,  A,  P0);
    matmul128_kernel<<<128, 128, 0, stream>>>(P0, P0, P1);
    matmul128_kernel<<<128, 128, 0, stream>>>(P1, P1, P0);
    matmul128_kernel<<<128, 128, 0, stream>>>(P0, P0, P1);
    matmul128_kernel<<<128, 128, 0, stream>>>(P1, P1, P0);
    matmul128_kernel<<<128, 128, 0, stream>>>(P0, P0, P1);
    phase1_kernel<<<NC * BATCH / 2, 256, 0, stream>>>(u_, A, Bm, L);
    phase2_kernel<<<BATCH, 128, 0, stream>>>(P1, L, x0, Xc);
    phase3_kernel<<<NC * BATCH / 2, 256, 0, stream>>>(u_, A, Bm, C, Xc, y);
}

// Round 2
// 789.133 us; speedup vs baseline: 1.2643x; 1.2643x over previous
//
#include <hip/hip_runtime.h>

#define BATCH 32
#define T_LEN 4096
#define NU 64
#define NX 128
#define NY 64
#define KCH 64
#define NC (T_LEN / KCH)   /* 64 chunks */

/* workspace float offsets */
#define OFF_E   0
#define OFF_F   16384
#define OFF_A   32768
#define OFF_P0  49152
#define OFF_P1  65536
#define OFF_L   81920                 /* NC*BATCH*NX = 262144 floats */
#define OFF_XC  (81920 + 262144)     /* NC*BATCH*NX = 262144 floats */

/* ---- K1: E = 0.5*(S22+S11)+1e-9 I, F = S21, from M (256x256) ---- */
__global__ void ef_kernel(const float* __restrict__ M, float* __restrict__ E,
                          float* __restrict__ F) {
    int i = blockIdx.x;      // row 0..127
    int j = threadIdx.x;     // col 0..127
    const float* Mi2 = M + (size_t)(128 + i) * 256;
    const float* Mj1 = M + (size_t)j * 256;
    if (blockIdx.y == 0) {
        const float* Mi1 = M + (size_t)i * 256;
        const float* Mj2 = M + (size_t)(128 + j) * 256;
        float s11 = 0.f, s22 = 0.f;
        for (int m = 0; m < 256; ++m) {
            s11 += Mi1[m] * Mj1[m];
            s22 += Mi2[m] * Mj2[m];
        }
        float e = 0.5f * (s11 + s22);
        if (i == j) e += 1e-9f;
        E[i * NX + j] = e;
    } else {
        float s21 = 0.f;
        for (int m = 0; m < 256; ++m) s21 += Mi2[m] * Mj1[m];
        F[i * NX + j] = s21;
    }
}

/* ---- K2: solve E * A = F by Gaussian elimination (E SPD, no pivoting) ---- */
__global__ __launch_bounds__(256) void solve_kernel(const float* __restrict__ E,
                                                    const float* __restrict__ F,
                                                    float* __restrict__ A) {
    __shared__ float aug[NX][2 * NX + 2];   // cols 0..127 = E, 128..255 = F->A
    int tid = threadIdx.x;
    for (int idx = tid; idx < NX * NX; idx += 256) {
        int i = idx >> 7, j = idx & 127;
        aug[i][j] = E[idx];
        aug[i][NX + j] = F[idx];
    }
    /* forward elimination */
    for (int k = 0; k < NX; ++k) {
        __syncthreads();
        float invp = 1.0f / aug[k][k];
        for (int i = k + 1 + (tid >> 1); i < NX; i += 128) {
            float m = aug[i][k] * invp;
            for (int j = k + 1 + (tid & 1); j < 2 * NX; j += 2)
                aug[i][j] -= m * aug[k][j];
        }
    }
    /* back substitution: rows high->low, result into cols 128..255 */
    for (int k = NX - 1; k >= 0; --k) {
        __syncthreads();
        if (tid < NX) {
            float invp = 1.0f / aug[k][k];
            float s = aug[k][NX + tid];
            for (int i = k + 1; i < NX; ++i) s -= aug[k][i] * aug[i][NX + tid];
            aug[k][NX + tid] = s * invp;
        }
    }
    __syncthreads();
    for (int idx = tid; idx < NX * NX; idx += 256)
        A[idx] = aug[idx >> 7][NX + (idx & 127)];
}

/* ---- K3: Z = X*Y, 128x128 fp32 ---- */
__global__ void matmul128_kernel(const float* __restrict__ X,
                                 const float* __restrict__ Y,
                                 float* __restrict__ Z) {
    int i = blockIdx.x, j = threadIdx.x;
    float a0 = 0.f, a1 = 0.f, a2 = 0.f, a3 = 0.f;
    for (int m = 0; m < NX; m += 4) {
        a0 += X[i * NX + m]     * Y[(m)     * NX + j];
        a1 += X[i * NX + m + 1] * Y[(m + 1) * NX + j];
        a2 += X[i * NX + m + 2] * Y[(m + 2) * NX + j];
        a3 += X[i * NX + m + 3] * Y[(m + 3) * NX + j];
    }
    Z[i * NX + j] = (a0 + a1) + (a2 + a3);
}

/* ---- K4: phase 1 — local chunk scans from zero state (A,B in registers) ----
   One (chunk,batch) pair per 256-thread block. Thread (i=t>>1, h=t&1) holds
   A[i][h*64..h*64+63] and B[i][h*32..h*32+31] in VGPRs. x broadcast via LDS. */
__global__ __launch_bounds__(256) void phase1_kernel(const float* __restrict__ u_,
                                                     const float* __restrict__ A,
                                                     const float* __restrict__ Bm,
                                                     float* __restrict__ L) {
    int t = threadIdx.x;
    int i = t >> 1, h = t & 1;
    int pair = blockIdx.x;          // pair = c*BATCH + b
    int c = pair >> 5, b = pair & 31;
    const float* urow = u_ + ((size_t)b * T_LEN + (size_t)c * KCH) * NU;

    float Ar[64];
    {
        const float4* Arow = (const float4*)(A + (size_t)i * NX + h * 64);
#pragma unroll
        for (int j4 = 0; j4 < 16; ++j4) {
            float4 v = Arow[j4];
            Ar[4 * j4] = v.x; Ar[4 * j4 + 1] = v.y; Ar[4 * j4 + 2] = v.z; Ar[4 * j4 + 3] = v.w;
        }
    }
    float Br[32];
    {
        const float4* Brow = (const float4*)(Bm + (size_t)i * NU + h * 32);
#pragma unroll
        for (int j4 = 0; j4 < 8; ++j4) {
            float4 v = Brow[j4];
            Br[4 * j4] = v.x; Br[4 * j4 + 1] = v.y; Br[4 * j4 + 2] = v.z; Br[4 * j4 + 3] = v.w;
        }
    }

    __shared__ float xs[2][NX];
    __shared__ float us[2][NU];
    if (h == 0) xs[0][i] = 0.f;
    float up = (t < NU) ? urow[t] : 0.f;   // u[cK + 0]

    int buf = 0;
    float s = 0.f;
    for (int m = 0; m < KCH; ++m) {
        if (t < NU) us[buf][t] = up;
        if (m < KCH - 1 && t < NU) up = urow[(m + 1) * NU + t];  // prefetch
        __syncthreads();
        float a0 = 0.f, a1 = 0.f, a2 = 0.f, a3 = 0.f;
        const float* xp = &xs[buf][h * 64];
        const float* upp = &us[buf][h * 32];
#pragma unroll
        for (int j = 0; j < 64; j += 4) {
            a0 += Ar[j]     * xp[j];
            a1 += Ar[j + 1] * xp[j + 1];
            a2 += Ar[j + 2] * xp[j + 2];
            a3 += Ar[j + 3] * xp[j + 3];
        }
#pragma unroll
        for (int j = 0; j < 32; j += 4) {
            a0 += Br[j]     * upp[j];
            a1 += Br[j + 1] * upp[j + 1];
            a2 += Br[j + 2] * upp[j + 2];
            a3 += Br[j + 3] * upp[j + 3];
        }
        float a = (a0 + a1) + (a2 + a3);
        s = a + __shfl_xor(a, 1);
        if (h == 0) xs[buf ^ 1][i] = s;
        buf ^= 1;
    }
    if (h == 0) L[(size_t)pair * NX + i] = s;
}

/* ---- K5: phase 2 — chunk-level recurrence Xc[c+1] = A^K Xc[c] + L[c] ---- */
__global__ __launch_bounds__(128) void phase2_kernel(const float* __restrict__ AK,
                                                     const float* __restrict__ L,
                                                     const float* __restrict__ x0,
                                                     float* __restrict__ Xc) {
    __shared__ float Ks[NX][NX + 1];
    __shared__ float xs[NX];
    int tid = threadIdx.x, b = blockIdx.x;
    for (int idx = tid; idx < NX * NX; idx += 128)
        Ks[idx >> 7][idx & 127] = AK[idx];
    float x = x0[tid];
    xs[tid] = x;
    Xc[(size_t)(0 * BATCH + b) * NX + tid] = x;
    __syncthreads();
    for (int c = 0; c < NC - 1; ++c) {
        float a0 = 0.f, a1 = 0.f, a2 = 0.f, a3 = 0.f;
        for (int j = 0; j < NX; j += 4) {
            a0 += Ks[tid][j]     * xs[j];
            a1 += Ks[tid][j + 1] * xs[j + 1];
            a2 += Ks[tid][j + 2] * xs[j + 2];
            a3 += Ks[tid][j + 3] * xs[j + 3];
        }
        float xn = (a0 + a1) + (a2 + a3) + L[((size_t)c * BATCH + b) * NX + tid];
        __syncthreads();
        xs[tid] = xn;
        Xc[((size_t)(c + 1) * BATCH + b) * NX + tid] = xn;
        __syncthreads();
    }
}

/* ---- K6: phase 3 — re-run chunks from true start state, emit y = C x ----
   Same register-A layout as phase1; additionally thread (r=t>>2, q=t&3)
   holds C[r][q*32..q*32+31] for the y-emit. */
__global__ __launch_bounds__(256) void phase3_kernel(const float* __restrict__ u_,
                                                     const float* __restrict__ A,
                                                     const float* __restrict__ Bm,
                                                     const float* __restrict__ C,
                                                     const float* __restrict__ Xc,
                                                     float* __restrict__ y) {
    int t = threadIdx.x;
    int i = t >> 1, h = t & 1;
    int r = t >> 2, q = t & 3;
    int pair = blockIdx.x;
    int c = pair >> 5, b = pair & 31;
    const float* urow = u_ + ((size_t)b * T_LEN + (size_t)c * KCH) * NU;
    float* yrow = y + ((size_t)b * T_LEN + (size_t)c * KCH) * NY;

    float Ar[64];
    {
        const float4* Arow = (const float4*)(A + (size_t)i * NX + h * 64);
#pragma unroll
        for (int j4 = 0; j4 < 16; ++j4) {
            float4 v = Arow[j4];
            Ar[4 * j4] = v.x; Ar[4 * j4 + 1] = v.y; Ar[4 * j4 + 2] = v.z; Ar[4 * j4 + 3] = v.w;
        }
    }
    float Br[32];
    {
        const float4* Brow = (const float4*)(Bm + (size_t)i * NU + h * 32);
#pragma unroll
        for (int j4 = 0; j4 < 8; ++j4) {
            float4 v = Brow[j4];
            Br[4 * j4] = v.x; Br[4 * j4 + 1] = v.y; Br[4 * j4 + 2] = v.z; Br[4 * j4 + 3] = v.w;
        }
    }
    float Cr[32];
    {
        const float4* Crow = (const float4*)(C + (size_t)r * NX + q * 32);
#pragma unroll
        for (int j4 = 0; j4 < 8; ++j4) {
            float4 v = Crow[j4];
            Cr[4 * j4] = v.x; Cr[4 * j4 + 1] = v.y; Cr[4 * j4 + 2] = v.z; Cr[4 * j4 + 3] = v.w;
        }
    }

    __shared__ float xs[2][NX];
    __shared__ float us[2][NU];
    if (h == 0) xs[0][i] = Xc[(size_t)pair * NX + i];
    float up = (t < NU) ? urow[t] : 0.f;   // u[cK + 0] (used at k=1)
    __syncthreads();

    /* emit k = 0 from xs[0] */
    {
        float c0 = 0.f, c1 = 0.f, c2 = 0.f, c3 = 0.f;
        const float* xp = &xs[0][q * 32];
#pragma unroll
        for (int j = 0; j < 32; j += 4) {
            c0 += Cr[j]     * xp[j];
            c1 += Cr[j + 1] * xp[j + 1];
            c2 += Cr[j + 2] * xp[j + 2];
            c3 += Cr[j + 3] * xp[j + 3];
        }
        float s = (c0 + c1) + (c2 + c3);
        s += __shfl_xor(s, 1);
        s += __shfl_xor(s, 2);
        if (q == 0) yrow[r] = s;
    }

    int buf = 0;
    for (int k = 1; k < KCH; ++k) {
        if (t < NU) us[buf][t] = up;
        if (k < KCH - 1 && t < NU) up = urow[(size_t)k * NU + t];  // u[cK+k] for next iter
        __syncthreads();
        float a0 = 0.f, a1 = 0.f, a2 = 0.f, a3 = 0.f;
        const float* xp = &xs[buf][h * 64];
        const float* upp = &us[buf][h * 32];
#pragma unroll
        for (int j = 0; j < 64; j += 4) {
            a0 += Ar[j]     * xp[j];
            a1 += Ar[j + 1] * xp[j + 1];
            a2 += Ar[j + 2] * xp[j + 2];
            a3 += Ar[j + 3] * xp[j + 3];
        }
#pragma unroll
        for (int j = 0; j < 32; j += 4) {
            a0 += Br[j]     * upp[j];
            a1 += Br[j + 1] * upp[j + 1];
            a2 += Br[j + 2] * upp[j + 2];
            a3 += Br[j + 3] * upp[j + 3];
        }
        float a = (a0 + a1) + (a2 + a3);
        float s = a + __shfl_xor(a, 1);
        if (h == 0) xs[buf ^ 1][i] = s;
        __syncthreads();
        /* emit k from xs[buf^1] */
        float c0 = 0.f, c1 = 0.f, c2 = 0.f, c3 = 0.f;
        const float* xcp = &xs[buf ^ 1][q * 32];
#pragma unroll
        for (int j = 0; j < 32; j += 4) {
            c0 += Cr[j]     * xcp[j];
            c1 += Cr[j + 1] * xcp[j + 1];
            c2 += Cr[j + 2] * xcp[j + 2];
            c3 += Cr[j + 3] * xcp[j + 3];
        }
        float sy = (c0 + c1) + (c2 + c3);
        sy += __shfl_xor(sy, 1);
        sy += __shfl_xor(sy, 2);
        if (q == 0) yrow[(size_t)k * NY + r] = sy;
        buf ^= 1;
    }
}

extern "C" void kernel_launch(void* const* d_in, const int* in_sizes, int n_in,
                              void* d_out, int out_size, void* d_ws, size_t ws_size,
                              hipStream_t stream) {
    const float* u_  = (const float*)d_in[0];
    const float* M   = (const float*)d_in[1];
    const float* Bm  = (const float*)d_in[2];
    const float* C   = (const float*)d_in[3];
    const float* x0  = (const float*)d_in[4];
    float* y = (float*)d_out;
    float* ws = (float*)d_ws;

    float* E  = ws + OFF_E;
    float* F  = ws + OFF_F;
    float* A  = ws + OFF_A;
    float* P0 = ws + OFF_P0;
    float* P1 = ws + OFF_P1;
    float* L  = ws + OFF_L;
    float* Xc = ws + OFF_XC;

    ef_kernel<<<dim3(128, 2), 128, 0, stream>>>(M, E, F);
    solve_kernel<<<1, 256, 0, stream>>>(E, F, A);
    /* A^64 by repeated squaring: A2,A4,A8,A16,A32,A64 */
    matmul128_kernel<<<128, 128, 0, stream>>>(A,  A,  P0);
    matmul128_kernel<<<128, 128, 0, stream>>>(P0, P0, P1);
    matmul128_kernel<<<128, 128, 0, stream>>>(P1, P1, P0);
    matmul128_kernel<<<128, 128, 0, stream>>>(P0, P0, P1);
    matmul128_kernel<<<128, 128, 0, stream>>>(P1, P1, P0);
    matmul128_kernel<<<128, 128, 0, stream>>>(P0, P0, P1);
    phase1_kernel<<<NC * BATCH, 256, 0, stream>>>(u_, A, Bm, L);
    phase2_kernel<<<BATCH, 128, 0, stream>>>(P1, L, x0, Xc);
    phase3_kernel<<<NC * BATCH, 256, 0, stream>>>(u_, A, Bm, C, Xc, y);
}

// Round 3
// 668.120 us; speedup vs baseline: 1.4933x; 1.1811x over previous
//
#include <hip/hip_runtime.h>

#define BATCH 32
#define T_LEN 4096
#define NU 64
#define NX 128
#define NY 64
#define KCH 64
#define NC (T_LEN / KCH)   /* 64 chunks */

/* workspace float offsets */
#define OFF_E   0
#define OFF_F   16384
#define OFF_A   32768
#define OFF_P0  49152
#define OFF_P1  65536
#define OFF_L   81920                 /* NC*BATCH*NX = 262144 floats */
#define OFF_XC  (81920 + 262144)     /* NC*BATCH*NX = 262144 floats */

/* ---- K1: E = 0.5*(S22+S11)+1e-9 I, F = S21, from M (256x256) ---- */
__global__ void ef_kernel(const float* __restrict__ M, float* __restrict__ E,
                          float* __restrict__ F) {
    int i = blockIdx.x;      // row 0..127
    int j = threadIdx.x;     // col 0..127
    const float* Mi2 = M + (size_t)(128 + i) * 256;
    const float* Mj1 = M + (size_t)j * 256;
    if (blockIdx.y == 0) {
        const float* Mi1 = M + (size_t)i * 256;
        const float* Mj2 = M + (size_t)(128 + j) * 256;
        float s11 = 0.f, s22 = 0.f;
        for (int m = 0; m < 256; ++m) {
            s11 += Mi1[m] * Mj1[m];
            s22 += Mi2[m] * Mj2[m];
        }
        float e = 0.5f * (s11 + s22);
        if (i == j) e += 1e-9f;
        E[i * NX + j] = e;
    } else {
        float s21 = 0.f;
        for (int m = 0; m < 256; ++m) s21 += Mi2[m] * Mj1[m];
        F[i * NX + j] = s21;
    }
}

/* ---- K2: solve E * A = F via register-resident Gauss-Jordan ----
   4 waves: waves {0,2} hold E-half rows, waves {1,3} hold F-half rows.
   Thread (h = wave&1, i = (wave>>1)*64 + lane) holds half-row i (128 floats)
   in 32 float4 VGPRs. Pivot row double-buffered in LDS (broadcast reads);
   multiplier column double-buffered. One barrier per step, 128 steps.
   No back-substitution: Gauss-Jordan leaves E-part diagonal; pivots are
   snapshotted into pivarr[k] at step k (before dead-column noise can touch
   them), final A row = F-half regs / pivarr[i]. */
__global__ __launch_bounds__(256) void solve_kernel(const float* __restrict__ E,
                                                    const float* __restrict__ F,
                                                    float* __restrict__ A) {
    __shared__ __align__(16) float prow[2][256];
    __shared__ float mraw[2][128];
    __shared__ float pivarr[128];
    int t = threadIdx.x;
    int w = t >> 6, lane = t & 63;
    int h = w & 1, rb = w >> 1;
    int i = rb * 64 + lane;
    const float4* src = (const float4*)((h == 0 ? E : F) + (size_t)i * NX);
    float4 R[32];
#pragma unroll
    for (int j4 = 0; j4 < 32; ++j4) R[j4] = src[j4];
    /* init step-0 pivot row and multiplier column */
    if (i == 0) {
        float4* p4 = (float4*)&prow[0][h * 128];
#pragma unroll
        for (int j4 = 0; j4 < 32; ++j4) p4[j4] = R[j4];
    }
    if (h == 0) mraw[0][i] = R[0].x;
    __syncthreads();

    for (int k = 0; k < NX; ++k) {
        int cur = k & 1, nxt = cur ^ 1;
        float piv = prow[cur][k];
        if (h == 0 && i == k) pivarr[k] = piv;
        float invp = 1.0f / piv;
        float m = mraw[cur][i] * invp;
        m = (i == k) ? 0.0f : m;
        const float4* p4 = (const float4*)&prow[cur][h * 128];
#pragma unroll
        for (int j4 = 0; j4 < 32; ++j4) {
            float4 p = p4[j4];
            R[j4].x -= m * p.x;
            R[j4].y -= m * p.y;
            R[j4].z -= m * p.z;
            R[j4].w -= m * p.w;
        }
        if (k < NX - 1) {
            if (i == k + 1) {
                float4* q4 = (float4*)&prow[nxt][h * 128];
#pragma unroll
                for (int j4 = 0; j4 < 32; ++j4) q4[j4] = R[j4];
            }
            if (h == 0) {
                int kq = (k + 1) >> 2, kr = (k + 1) & 3;
                float4 vv = R[0];
#pragma unroll
                for (int j4 = 1; j4 < 32; ++j4) if (j4 == kq) vv = R[j4];
                float val = (kr == 0) ? vv.x : (kr == 1) ? vv.y
                          : (kr == 2) ? vv.z : vv.w;
                mraw[nxt][i] = val;
            }
        }
        __syncthreads();
    }

    if (h == 1) {
        float s = 1.0f / pivarr[i];
        float4* dst = (float4*)(A + (size_t)i * NX);
#pragma unroll
        for (int j4 = 0; j4 < 32; ++j4) {
            float4 v = R[j4];
            v.x *= s; v.y *= s; v.z *= s; v.w *= s;
            dst[j4] = v;
        }
    }
}

/* ---- K3: Z = X*Y, 128x128 fp32 ---- */
__global__ void matmul128_kernel(const float* __restrict__ X,
                                 const float* __restrict__ Y,
                                 float* __restrict__ Z) {
    int i = blockIdx.x, j = threadIdx.x;
    float a0 = 0.f, a1 = 0.f, a2 = 0.f, a3 = 0.f;
    for (int m = 0; m < NX; m += 4) {
        a0 += X[i * NX + m]     * Y[(m)     * NX + j];
        a1 += X[i * NX + m + 1] * Y[(m + 1) * NX + j];
        a2 += X[i * NX + m + 2] * Y[(m + 2) * NX + j];
        a3 += X[i * NX + m + 3] * Y[(m + 3) * NX + j];
    }
    Z[i * NX + j] = (a0 + a1) + (a2 + a3);
}

/* ---- K4: phase 1 — local chunk scans from zero state (A,B in registers) ---- */
__global__ __launch_bounds__(256) void phase1_kernel(const float* __restrict__ u_,
                                                     const float* __restrict__ A,
                                                     const float* __restrict__ Bm,
                                                     float* __restrict__ L) {
    int t = threadIdx.x;
    int i = t >> 1, h = t & 1;
    int pair = blockIdx.x;          // pair = c*BATCH + b
    int c = pair >> 5, b = pair & 31;
    const float* urow = u_ + ((size_t)b * T_LEN + (size_t)c * KCH) * NU;

    float Ar[64];
    {
        const float4* Arow = (const float4*)(A + (size_t)i * NX + h * 64);
#pragma unroll
        for (int j4 = 0; j4 < 16; ++j4) {
            float4 v = Arow[j4];
            Ar[4 * j4] = v.x; Ar[4 * j4 + 1] = v.y; Ar[4 * j4 + 2] = v.z; Ar[4 * j4 + 3] = v.w;
        }
    }
    float Br[32];
    {
        const float4* Brow = (const float4*)(Bm + (size_t)i * NU + h * 32);
#pragma unroll
        for (int j4 = 0; j4 < 8; ++j4) {
            float4 v = Brow[j4];
            Br[4 * j4] = v.x; Br[4 * j4 + 1] = v.y; Br[4 * j4 + 2] = v.z; Br[4 * j4 + 3] = v.w;
        }
    }

    __shared__ float xs[2][NX];
    __shared__ float us[2][NU];
    if (h == 0) xs[0][i] = 0.f;
    float up = (t < NU) ? urow[t] : 0.f;   // u[cK + 0]

    int buf = 0;
    float s = 0.f;
    for (int m = 0; m < KCH; ++m) {
        if (t < NU) us[buf][t] = up;
        if (m < KCH - 1 && t < NU) up = urow[(m + 1) * NU + t];  // prefetch
        __syncthreads();
        float a0 = 0.f, a1 = 0.f, a2 = 0.f, a3 = 0.f;
        const float* xp = &xs[buf][h * 64];
        const float* upp = &us[buf][h * 32];
#pragma unroll
        for (int j = 0; j < 64; j += 4) {
            a0 += Ar[j]     * xp[j];
            a1 += Ar[j + 1] * xp[j + 1];
            a2 += Ar[j + 2] * xp[j + 2];
            a3 += Ar[j + 3] * xp[j + 3];
        }
#pragma unroll
        for (int j = 0; j < 32; j += 4) {
            a0 += Br[j]     * upp[j];
            a1 += Br[j + 1] * upp[j + 1];
            a2 += Br[j + 2] * upp[j + 2];
            a3 += Br[j + 3] * upp[j + 3];
        }
        float a = (a0 + a1) + (a2 + a3);
        s = a + __shfl_xor(a, 1);
        if (h == 0) xs[buf ^ 1][i] = s;
        buf ^= 1;
    }
    if (h == 0) L[(size_t)pair * NX + i] = s;
}

/* ---- K5: phase 2 — chunk-level recurrence Xc[c+1] = A^K Xc[c] + L[c] ---- */
__global__ __launch_bounds__(128) void phase2_kernel(const float* __restrict__ AK,
                                                     const float* __restrict__ L,
                                                     const float* __restrict__ x0,
                                                     float* __restrict__ Xc) {
    __shared__ float Ks[NX][NX + 1];
    __shared__ float xs[NX];
    int tid = threadIdx.x, b = blockIdx.x;
    for (int idx = tid; idx < NX * NX; idx += 128)
        Ks[idx >> 7][idx & 127] = AK[idx];
    float x = x0[tid];
    xs[tid] = x;
    Xc[(size_t)(0 * BATCH + b) * NX + tid] = x;
    __syncthreads();
    for (int c = 0; c < NC - 1; ++c) {
        float a0 = 0.f, a1 = 0.f, a2 = 0.f, a3 = 0.f;
        for (int j = 0; j < NX; j += 4) {
            a0 += Ks[tid][j]     * xs[j];
            a1 += Ks[tid][j + 1] * xs[j + 1];
            a2 += Ks[tid][j + 2] * xs[j + 2];
            a3 += Ks[tid][j + 3] * xs[j + 3];
        }
        float xn = (a0 + a1) + (a2 + a3) + L[((size_t)c * BATCH + b) * NX + tid];
        __syncthreads();
        xs[tid] = xn;
        Xc[((size_t)(c + 1) * BATCH + b) * NX + tid] = xn;
        __syncthreads();
    }
}

/* ---- K6: phase 3 — re-run chunks from true start state, emit y = C x ---- */
__global__ __launch_bounds__(256) void phase3_kernel(const float* __restrict__ u_,
                                                     const float* __restrict__ A,
                                                     const float* __restrict__ Bm,
                                                     const float* __restrict__ C,
                                                     const float* __restrict__ Xc,
                                                     float* __restrict__ y) {
    int t = threadIdx.x;
    int i = t >> 1, h = t & 1;
    int r = t >> 2, q = t & 3;
    int pair = blockIdx.x;
    int c = pair >> 5, b = pair & 31;
    const float* urow = u_ + ((size_t)b * T_LEN + (size_t)c * KCH) * NU;
    float* yrow = y + ((size_t)b * T_LEN + (size_t)c * KCH) * NY;

    float Ar[64];
    {
        const float4* Arow = (const float4*)(A + (size_t)i * NX + h * 64);
#pragma unroll
        for (int j4 = 0; j4 < 16; ++j4) {
            float4 v = Arow[j4];
            Ar[4 * j4] = v.x; Ar[4 * j4 + 1] = v.y; Ar[4 * j4 + 2] = v.z; Ar[4 * j4 + 3] = v.w;
        }
    }
    float Br[32];
    {
        const float4* Brow = (const float4*)(Bm + (size_t)i * NU + h * 32);
#pragma unroll
        for (int j4 = 0; j4 < 8; ++j4) {
            float4 v = Brow[j4];
            Br[4 * j4] = v.x; Br[4 * j4 + 1] = v.y; Br[4 * j4 + 2] = v.z; Br[4 * j4 + 3] = v.w;
        }
    }
    float Cr[32];
    {
        const float4* Crow = (const float4*)(C + (size_t)r * NX + q * 32);
#pragma unroll
        for (int j4 = 0; j4 < 8; ++j4) {
            float4 v = Crow[j4];
            Cr[4 * j4] = v.x; Cr[4 * j4 + 1] = v.y; Cr[4 * j4 + 2] = v.z; Cr[4 * j4 + 3] = v.w;
        }
    }

    __shared__ float xs[2][NX];
    __shared__ float us[2][NU];
    if (h == 0) xs[0][i] = Xc[(size_t)pair * NX + i];
    float up = (t < NU) ? urow[t] : 0.f;   // u[cK + 0] (used at k=1)
    __syncthreads();

    /* emit k = 0 from xs[0] */
    {
        float c0 = 0.f, c1 = 0.f, c2 = 0.f, c3 = 0.f;
        const float* xp = &xs[0][q * 32];
#pragma unroll
        for (int j = 0; j < 32; j += 4) {
            c0 += Cr[j]     * xp[j];
            c1 += Cr[j + 1] * xp[j + 1];
            c2 += Cr[j + 2] * xp[j + 2];
            c3 += Cr[j + 3] * xp[j + 3];
        }
        float s = (c0 + c1) + (c2 + c3);
        s += __shfl_xor(s, 1);
        s += __shfl_xor(s, 2);
        if (q == 0) yrow[r] = s;
    }

    int buf = 0;
    for (int k = 1; k < KCH; ++k) {
        if (t < NU) us[buf][t] = up;
        if (k < KCH - 1 && t < NU) up = urow[(size_t)k * NU + t];  // u[cK+k] for next iter
        __syncthreads();
        float a0 = 0.f, a1 = 0.f, a2 = 0.f, a3 = 0.f;
        const float* xp = &xs[buf][h * 64];
        const float* upp = &us[buf][h * 32];
#pragma unroll
        for (int j = 0; j < 64; j += 4) {
            a0 += Ar[j]     * xp[j];
            a1 += Ar[j + 1] * xp[j + 1];
            a2 += Ar[j + 2] * xp[j + 2];
            a3 += Ar[j + 3] * xp[j + 3];
        }
#pragma unroll
        for (int j = 0; j < 32; j += 4) {
            a0 += Br[j]     * upp[j];
            a1 += Br[j + 1] * upp[j + 1];
            a2 += Br[j + 2] * upp[j + 2];
            a3 += Br[j + 3] * upp[j + 3];
        }
        float a = (a0 + a1) + (a2 + a3);
        float s = a + __shfl_xor(a, 1);
        if (h == 0) xs[buf ^ 1][i] = s;
        __syncthreads();
        /* emit k from xs[buf^1] */
        float c0 = 0.f, c1 = 0.f, c2 = 0.f, c3 = 0.f;
        const float* xcp = &xs[buf ^ 1][q * 32];
#pragma unroll
        for (int j = 0; j < 32; j += 4) {
            c0 += Cr[j]     * xcp[j];
            c1 += Cr[j + 1] * xcp[j + 1];
            c2 += Cr[j + 2] * xcp[j + 2];
            c3 += Cr[j + 3] * xcp[j + 3];
        }
        float sy = (c0 + c1) + (c2 + c3);
        sy += __shfl_xor(sy, 1);
        sy += __shfl_xor(sy, 2);
        if (q == 0) yrow[(size_t)k * NY + r] = sy;
        buf ^= 1;
    }
}

extern "C" void kernel_launch(void* const* d_in, const int* in_sizes, int n_in,
                              void* d_out, int out_size, void* d_ws, size_t ws_size,
                              hipStream_t stream) {
    const float* u_  = (const float*)d_in[0];
    const float* M   = (const float*)d_in[1];
    const float* Bm  = (const float*)d_in[2];
    const float* C   = (const float*)d_in[3];
    const float* x0  = (const float*)d_in[4];
    float* y = (float*)d_out;
    float* ws = (float*)d_ws;

    float* E  = ws + OFF_E;
    float* F  = ws + OFF_F;
    float* A  = ws + OFF_A;
    float* P0 = ws + OFF_P0;
    float* P1 = ws + OFF_P1;
    float* L  = ws + OFF_L;
    float* Xc = ws + OFF_XC;

    ef_kernel<<<dim3(128, 2), 128, 0, stream>>>(M, E, F);
    solve_kernel<<<1, 256, 0, stream>>>(E, F, A);
    /* A^64 by repeated squaring: A2,A4,A8,A16,A32,A64 */
    matmul128_kernel<<<128, 128, 0, stream>>>(A,  A,  P0);
    matmul128_kernel<<<128, 128, 0, stream>>>(P0, P0, P1);
    matmul128_kernel<<<128, 128, 0, stream>>>(P1, P1, P0);
    matmul128_kernel<<<128, 128, 0, stream>>>(P0, P0, P1);
    matmul128_kernel<<<128, 128, 0, stream>>>(P1, P1, P0);
    matmul128_kernel<<<128, 128, 0, stream>>>(P0, P0, P1);
    phase1_kernel<<<NC * BATCH, 256, 0, stream>>>(u_, A, Bm, L);
    phase2_kernel<<<BATCH, 128, 0, stream>>>(P1, L, x0, Xc);
    phase3_kernel<<<NC * BATCH, 256, 0, stream>>>(u_, A, Bm, C, Xc, y);
}

// Round 4
// 567.196 us; speedup vs baseline: 1.7590x; 1.1779x over previous
//
#include <hip/hip_runtime.h>

#define BATCH 32
#define T_LEN 4096
#define NU 64
#define NX 128
#define NY 64
#define KCH 64
#define NC (T_LEN / KCH)   /* 64 chunks */

/* workspace float offsets */
#define OFF_E   0
#define OFF_F   16384
#define OFF_A   32768
#define OFF_P0  49152
#define OFF_P1  65536
#define OFF_L   81920                  /* NC*BATCH*NX = 262144 floats */
#define OFF_XC  (81920 + 262144)       /* NC*BATCH*NX = 262144 floats */
#define OFF_XT  (81920 + 262144 + 262144)
#define XT_FLOATS ((size_t)NC * BATCH * KCH * NX)   /* 16,777,216 floats */

/* ---- K1: E = 0.5*(S22+S11)+1e-9 I, F = S21, from M (256x256) ---- */
__global__ void ef_kernel(const float* __restrict__ M, float* __restrict__ E,
                          float* __restrict__ F) {
    int i = blockIdx.x;      // row 0..127
    int j = threadIdx.x;     // col 0..127
    const float* Mi2 = M + (size_t)(128 + i) * 256;
    const float* Mj1 = M + (size_t)j * 256;
    if (blockIdx.y == 0) {
        const float* Mi1 = M + (size_t)i * 256;
        const float* Mj2 = M + (size_t)(128 + j) * 256;
        float s11 = 0.f, s22 = 0.f;
        for (int m = 0; m < 256; ++m) {
            s11 += Mi1[m] * Mj1[m];
            s22 += Mi2[m] * Mj2[m];
        }
        float e = 0.5f * (s11 + s22);
        if (i == j) e += 1e-9f;
        E[i * NX + j] = e;
    } else {
        float s21 = 0.f;
        for (int m = 0; m < 256; ++m) s21 += Mi2[m] * Mj1[m];
        F[i * NX + j] = s21;
    }
}

/* ---- K2: solve E * A = F via register-resident Gauss-Jordan ---- */
__global__ __launch_bounds__(256) void solve_kernel(const float* __restrict__ E,
                                                    const float* __restrict__ F,
                                                    float* __restrict__ A) {
    __shared__ __align__(16) float prow[2][256];
    __shared__ float mraw[2][128];
    __shared__ float pivarr[128];
    int t = threadIdx.x;
    int w = t >> 6, lane = t & 63;
    int h = w & 1, rb = w >> 1;
    int i = rb * 64 + lane;
    const float4* src = (const float4*)((h == 0 ? E : F) + (size_t)i * NX);
    float4 R[32];
#pragma unroll
    for (int j4 = 0; j4 < 32; ++j4) R[j4] = src[j4];
    if (i == 0) {
        float4* p4 = (float4*)&prow[0][h * 128];
#pragma unroll
        for (int j4 = 0; j4 < 32; ++j4) p4[j4] = R[j4];
    }
    if (h == 0) mraw[0][i] = R[0].x;
    __syncthreads();

    for (int k = 0; k < NX; ++k) {
        int cur = k & 1, nxt = cur ^ 1;
        float piv = prow[cur][k];
        if (h == 0 && i == k) pivarr[k] = piv;
        float invp = 1.0f / piv;
        float m = mraw[cur][i] * invp;
        m = (i == k) ? 0.0f : m;
        const float4* p4 = (const float4*)&prow[cur][h * 128];
#pragma unroll
        for (int j4 = 0; j4 < 32; ++j4) {
            float4 p = p4[j4];
            R[j4].x -= m * p.x;
            R[j4].y -= m * p.y;
            R[j4].z -= m * p.z;
            R[j4].w -= m * p.w;
        }
        if (k < NX - 1) {
            if (i == k + 1) {
                float4* q4 = (float4*)&prow[nxt][h * 128];
#pragma unroll
                for (int j4 = 0; j4 < 32; ++j4) q4[j4] = R[j4];
            }
            if (h == 0) {
                int kq = (k + 1) >> 2, kr = (k + 1) & 3;
                float4 vv = R[0];
#pragma unroll
                for (int j4 = 1; j4 < 32; ++j4) if (j4 == kq) vv = R[j4];
                float val = (kr == 0) ? vv.x : (kr == 1) ? vv.y
                          : (kr == 2) ? vv.z : vv.w;
                mraw[nxt][i] = val;
            }
        }
        __syncthreads();
    }

    if (h == 1) {
        float s = 1.0f / pivarr[i];
        float4* dst = (float4*)(A + (size_t)i * NX);
#pragma unroll
        for (int j4 = 0; j4 < 32; ++j4) {
            float4 v = R[j4];
            v.x *= s; v.y *= s; v.z *= s; v.w *= s;
            dst[j4] = v;
        }
    }
}

/* ---- K3: Z = X*Y, 128x128 fp32 ---- */
__global__ void matmul128_kernel(const float* __restrict__ X,
                                 const float* __restrict__ Y,
                                 float* __restrict__ Z) {
    int i = blockIdx.x, j = threadIdx.x;
    float a0 = 0.f, a1 = 0.f, a2 = 0.f, a3 = 0.f;
    for (int m = 0; m < NX; m += 4) {
        a0 += X[i * NX + m]     * Y[(m)     * NX + j];
        a1 += X[i * NX + m + 1] * Y[(m + 1) * NX + j];
        a2 += X[i * NX + m + 2] * Y[(m + 2) * NX + j];
        a3 += X[i * NX + m + 3] * Y[(m + 3) * NX + j];
    }
    Z[i * NX + j] = (a0 + a1) + (a2 + a3);
}

/* ======== R4 scan layout ========
   256 threads; thread (g = t>>3, seg = t&7) owns rows {g,g+32,g+64,g+96},
   A-cols seg*16..+15 (64 VGPRs), B-cols seg*8..+7 (32 VGPRs).
   Per step: 96 reg-FMAs, 24 LDS floats read, xor-butterfly over 8 lanes,
   seg==0 writes the 4 combined rows. One barrier per step. */

#define SCAN_LOAD_AB()                                                         \
    float4 Ar[4][4];                                                           \
    float4 Br[4][2];                                                           \
    _Pragma("unroll")                                                          \
    for (int r = 0; r < 4; ++r) {                                              \
        const float4* ap = (const float4*)(A + (size_t)(g + 32 * r) * NX + seg * 16); \
        Ar[r][0] = ap[0]; Ar[r][1] = ap[1]; Ar[r][2] = ap[2]; Ar[r][3] = ap[3];\
        const float4* bp = (const float4*)(Bm + (size_t)(g + 32 * r) * NU + seg * 8); \
        Br[r][0] = bp[0]; Br[r][1] = bp[1];                                    \
    }

#define SCAN_STEP(BUFIDX)                                                      \
    {                                                                          \
        const float4* xp = (const float4*)&xs[BUFIDX][seg * 16];               \
        float4 x0 = xp[0], x1 = xp[1], x2 = xp[2], x3 = xp[3];                 \
        const float4* uq = (const float4*)&us[BUFIDX][seg * 8];                \
        float4 u0 = uq[0], u1 = uq[1];                                         \
        _Pragma("unroll")                                                      \
        for (int r = 0; r < 4; ++r) {                                          \
            float s0 = Ar[r][0].x * x0.x + Ar[r][0].y * x0.y                   \
                     + Ar[r][0].z * x0.z + Ar[r][0].w * x0.w;                  \
            float s1 = Ar[r][1].x * x1.x + Ar[r][1].y * x1.y                   \
                     + Ar[r][1].z * x1.z + Ar[r][1].w * x1.w;                  \
            float s2 = Ar[r][2].x * x2.x + Ar[r][2].y * x2.y                   \
                     + Ar[r][2].z * x2.z + Ar[r][2].w * x2.w;                  \
            float s3 = Ar[r][3].x * x3.x + Ar[r][3].y * x3.y                   \
                     + Ar[r][3].z * x3.z + Ar[r][3].w * x3.w;                  \
            s0 += Br[r][0].x * u0.x + Br[r][0].y * u0.y                        \
                + Br[r][0].z * u0.z + Br[r][0].w * u0.w;                       \
            s1 += Br[r][1].x * u1.x + Br[r][1].y * u1.y                        \
                + Br[r][1].z * u1.z + Br[r][1].w * u1.w;                       \
            acc[r] = (s0 + s1) + (s2 + s3);                                    \
        }                                                                      \
        _Pragma("unroll")                                                      \
        for (int d = 1; d <= 4; d <<= 1) {                                     \
            _Pragma("unroll")                                                  \
            for (int r = 0; r < 4; ++r) acc[r] += __shfl_xor(acc[r], d);       \
        }                                                                      \
        if (seg == 0) {                                                        \
            xs[BUFIDX ^ 1][g]      = acc[0];                                   \
            xs[BUFIDX ^ 1][g + 32] = acc[1];                                   \
            xs[BUFIDX ^ 1][g + 64] = acc[2];                                   \
            xs[BUFIDX ^ 1][g + 96] = acc[3];                                   \
        }                                                                      \
    }

/* ---- K4: phase 1 — local chunk scans from zero state; writes L ---- */
__global__ __launch_bounds__(256, 2) void phase1_kernel(const float* __restrict__ u_,
                                                        const float* __restrict__ A,
                                                        const float* __restrict__ Bm,
                                                        float* __restrict__ L) {
    int t = threadIdx.x;
    int g = t >> 3, seg = t & 7;
    int pair = blockIdx.x;          // pair = c*BATCH + b
    int c = pair >> 5, b = pair & 31;
    const float* urow = u_ + ((size_t)b * T_LEN + (size_t)c * KCH) * NU;
    SCAN_LOAD_AB();
    __shared__ __align__(16) float xs[2][NX];
    __shared__ __align__(16) float us[2][NU];
    if (t < NX) xs[0][t] = 0.f;
    float up = (t < NU) ? urow[t] : 0.f;
    int buf = 0;
    float acc[4];
    for (int m = 0; m < KCH; ++m) {
        if (t < NU) us[buf][t] = up;
        if (t < NU && m < KCH - 1) up = urow[(size_t)(m + 1) * NU + t];
        __syncthreads();
        SCAN_STEP(buf);
        buf ^= 1;
    }
    __syncthreads();
    if (t < NX) L[(size_t)pair * NX + t] = xs[buf][t];
}

/* ---- K5: phase 2 — chunk-level recurrence Xc[c+1] = A^K Xc[c] + L[c] ---- */
__global__ __launch_bounds__(128) void phase2_kernel(const float* __restrict__ AK,
                                                     const float* __restrict__ L,
                                                     const float* __restrict__ x0,
                                                     float* __restrict__ Xc) {
    __shared__ float Ks[NX][NX + 1];
    __shared__ float xs[NX];
    int tid = threadIdx.x, b = blockIdx.x;
    for (int idx = tid; idx < NX * NX; idx += 128)
        Ks[idx >> 7][idx & 127] = AK[idx];
    float x = x0[tid];
    xs[tid] = x;
    Xc[(size_t)(0 * BATCH + b) * NX + tid] = x;
    __syncthreads();
    for (int c = 0; c < NC - 1; ++c) {
        float a0 = 0.f, a1 = 0.f, a2 = 0.f, a3 = 0.f;
        for (int j = 0; j < NX; j += 4) {
            a0 += Ks[tid][j]     * xs[j];
            a1 += Ks[tid][j + 1] * xs[j + 1];
            a2 += Ks[tid][j + 2] * xs[j + 2];
            a3 += Ks[tid][j + 3] * xs[j + 3];
        }
        float xn = (a0 + a1) + (a2 + a3) + L[((size_t)c * BATCH + b) * NX + tid];
        __syncthreads();
        xs[tid] = xn;
        Xc[((size_t)(c + 1) * BATCH + b) * NX + tid] = xn;
        __syncthreads();
    }
}

/* ---- K6 (fast): phase 3 — re-run chunks, stream x_t to XT ---- */
__global__ __launch_bounds__(256, 2) void phase3x_kernel(const float* __restrict__ u_,
                                                         const float* __restrict__ A,
                                                         const float* __restrict__ Bm,
                                                         const float* __restrict__ Xc,
                                                         float* __restrict__ XT) {
    int t = threadIdx.x;
    int g = t >> 3, seg = t & 7;
    int pair = blockIdx.x;
    int c = pair >> 5, b = pair & 31;
    const float* urow = u_ + ((size_t)b * T_LEN + (size_t)c * KCH) * NU;
    SCAN_LOAD_AB();
    __shared__ __align__(16) float xs[2][NX];
    __shared__ __align__(16) float us[2][NU];
    if (t < NX) xs[0][t] = Xc[(size_t)pair * NX + t];
    float up = (t < NU) ? urow[t] : 0.f;   // u[cK+0], staged at m=1
    int buf = 0;
    float acc[4];
    for (int m = 1; m < KCH; ++m) {
        if (t < NU) us[buf][t] = up;
        if (t < NU && m < KCH - 1) up = urow[(size_t)m * NU + t];
        __syncthreads();
        if (t < NX) XT[((size_t)pair * KCH + (m - 1)) * NX + t] = xs[buf][t];
        SCAN_STEP(buf);
        buf ^= 1;
    }
    __syncthreads();
    if (t < NX) XT[((size_t)pair * KCH + (KCH - 1)) * NX + t] = xs[buf][t];
}

/* ---- K7 (fast): y = XT * C^T, tiled GEMM, one (c,b) pair per block ----
   M-tile 64 (prows), N 64 (y rows), K 128 split in 2 halves.
   Thread (pg = t>>4, rg = t&15) owns a 4x4 output tile. */
__global__ __launch_bounds__(256) void yemit_kernel(const float* __restrict__ XT,
                                                    const float* __restrict__ C,
                                                    float* __restrict__ y) {
    __shared__ __align__(16) float xt[64][68];
    __shared__ float ct[64][65];
    int t = threadIdx.x;
    int pair = blockIdx.x;
    int b = pair & 31, c = pair >> 5;
    int rg = t & 15, pg = t >> 4;
    float acc[4][4];
#pragma unroll
    for (int i = 0; i < 4; ++i)
#pragma unroll
        for (int j = 0; j < 4; ++j) acc[i][j] = 0.f;
    const float* xbase = XT + (size_t)pair * KCH * NX;
    for (int kh = 0; kh < 2; ++kh) {
        __syncthreads();
        for (int idx = t; idx < 64 * 16; idx += 256) {
            int p = idx >> 4, kq = idx & 15;
            float4 v = *(const float4*)(xbase + (size_t)p * NX + kh * 64 + kq * 4);
            *(float4*)&xt[p][kq * 4] = v;
            float4 w = *(const float4*)(C + (size_t)p * NX + kh * 64 + kq * 4);
            ct[p][kq * 4]     = w.x;
            ct[p][kq * 4 + 1] = w.y;
            ct[p][kq * 4 + 2] = w.z;
            ct[p][kq * 4 + 3] = w.w;
        }
        __syncthreads();
#pragma unroll 4
        for (int kc = 0; kc < 16; ++kc) {
            float4 xv[4];
#pragma unroll
            for (int pp = 0; pp < 4; ++pp)
                xv[pp] = *(const float4*)&xt[pg * 4 + pp][kc * 4];
#pragma unroll
            for (int rr = 0; rr < 4; ++rr) {
                const float* cr = &ct[rg * 4 + rr][kc * 4];
                float c0 = cr[0], c1 = cr[1], c2 = cr[2], c3 = cr[3];
#pragma unroll
                for (int pp = 0; pp < 4; ++pp)
                    acc[pp][rr] += xv[pp].x * c0 + xv[pp].y * c1
                                 + xv[pp].z * c2 + xv[pp].w * c3;
            }
        }
    }
    float* ybase = y + ((size_t)b * T_LEN + (size_t)c * KCH) * NY;
#pragma unroll
    for (int pp = 0; pp < 4; ++pp) {
        float4 o;
        o.x = acc[pp][0]; o.y = acc[pp][1]; o.z = acc[pp][2]; o.w = acc[pp][3];
        *(float4*)(ybase + (size_t)(pg * 4 + pp) * NY + rg * 4) = o;
    }
}

/* ---- K6b (fallback, ws too small): R3 phase3 with inline y-emit ---- */
__global__ __launch_bounds__(256) void phase3_fb_kernel(const float* __restrict__ u_,
                                                        const float* __restrict__ A,
                                                        const float* __restrict__ Bm,
                                                        const float* __restrict__ C,
                                                        const float* __restrict__ Xc,
                                                        float* __restrict__ y) {
    int t = threadIdx.x;
    int i = t >> 1, h = t & 1;
    int r = t >> 2, q = t & 3;
    int pair = blockIdx.x;
    int c = pair >> 5, b = pair & 31;
    const float* urow = u_ + ((size_t)b * T_LEN + (size_t)c * KCH) * NU;
    float* yrow = y + ((size_t)b * T_LEN + (size_t)c * KCH) * NY;
    float Ar[64];
    {
        const float4* Arow = (const float4*)(A + (size_t)i * NX + h * 64);
#pragma unroll
        for (int j4 = 0; j4 < 16; ++j4) {
            float4 v = Arow[j4];
            Ar[4 * j4] = v.x; Ar[4 * j4 + 1] = v.y; Ar[4 * j4 + 2] = v.z; Ar[4 * j4 + 3] = v.w;
        }
    }
    float Br[32];
    {
        const float4* Brow = (const float4*)(Bm + (size_t)i * NU + h * 32);
#pragma unroll
        for (int j4 = 0; j4 < 8; ++j4) {
            float4 v = Brow[j4];
            Br[4 * j4] = v.x; Br[4 * j4 + 1] = v.y; Br[4 * j4 + 2] = v.z; Br[4 * j4 + 3] = v.w;
        }
    }
    float Cr[32];
    {
        const float4* Crow = (const float4*)(C + (size_t)r * NX + q * 32);
#pragma unroll
        for (int j4 = 0; j4 < 8; ++j4) {
            float4 v = Crow[j4];
            Cr[4 * j4] = v.x; Cr[4 * j4 + 1] = v.y; Cr[4 * j4 + 2] = v.z; Cr[4 * j4 + 3] = v.w;
        }
    }
    __shared__ float xs[2][NX];
    __shared__ float us[2][NU];
    if (h == 0) xs[0][i] = Xc[(size_t)pair * NX + i];
    float up = (t < NU) ? urow[t] : 0.f;
    __syncthreads();
    {
        float c0 = 0.f, c1 = 0.f, c2 = 0.f, c3 = 0.f;
        const float* xp = &xs[0][q * 32];
#pragma unroll
        for (int j = 0; j < 32; j += 4) {
            c0 += Cr[j]     * xp[j];
            c1 += Cr[j + 1] * xp[j + 1];
            c2 += Cr[j + 2] * xp[j + 2];
            c3 += Cr[j + 3] * xp[j + 3];
        }
        float s = (c0 + c1) + (c2 + c3);
        s += __shfl_xor(s, 1);
        s += __shfl_xor(s, 2);
        if (q == 0) yrow[r] = s;
    }
    int buf = 0;
    for (int k = 1; k < KCH; ++k) {
        if (t < NU) us[buf][t] = up;
        if (k < KCH - 1 && t < NU) up = urow[(size_t)k * NU + t];
        __syncthreads();
        float a0 = 0.f, a1 = 0.f, a2 = 0.f, a3 = 0.f;
        const float* xp = &xs[buf][h * 64];
        const float* upp = &us[buf][h * 32];
#pragma unroll
        for (int j = 0; j < 64; j += 4) {
            a0 += Ar[j]     * xp[j];
            a1 += Ar[j + 1] * xp[j + 1];
            a2 += Ar[j + 2] * xp[j + 2];
            a3 += Ar[j + 3] * xp[j + 3];
        }
#pragma unroll
        for (int j = 0; j < 32; j += 4) {
            a0 += Br[j]     * upp[j];
            a1 += Br[j + 1] * upp[j + 1];
            a2 += Br[j + 2] * upp[j + 2];
            a3 += Br[j + 3] * upp[j + 3];
        }
        float a = (a0 + a1) + (a2 + a3);
        float s = a + __shfl_xor(a, 1);
        if (h == 0) xs[buf ^ 1][i] = s;
        __syncthreads();
        float c0 = 0.f, c1 = 0.f, c2 = 0.f, c3 = 0.f;
        const float* xcp = &xs[buf ^ 1][q * 32];
#pragma unroll
        for (int j = 0; j < 32; j += 4) {
            c0 += Cr[j]     * xcp[j];
            c1 += Cr[j + 1] * xcp[j + 1];
            c2 += Cr[j + 2] * xcp[j + 2];
            c3 += Cr[j + 3] * xcp[j + 3];
        }
        float sy = (c0 + c1) + (c2 + c3);
        sy += __shfl_xor(sy, 1);
        sy += __shfl_xor(sy, 2);
        if (q == 0) yrow[(size_t)k * NY + r] = sy;
        buf ^= 1;
    }
}

extern "C" void kernel_launch(void* const* d_in, const int* in_sizes, int n_in,
                              void* d_out, int out_size, void* d_ws, size_t ws_size,
                              hipStream_t stream) {
    const float* u_  = (const float*)d_in[0];
    const float* M   = (const float*)d_in[1];
    const float* Bm  = (const float*)d_in[2];
    const float* C   = (const float*)d_in[3];
    const float* x0  = (const float*)d_in[4];
    float* y = (float*)d_out;
    float* ws = (float*)d_ws;

    float* E  = ws + OFF_E;
    float* F  = ws + OFF_F;
    float* A  = ws + OFF_A;
    float* P0 = ws + OFF_P0;
    float* P1 = ws + OFF_P1;
    float* L  = ws + OFF_L;
    float* Xc = ws + OFF_XC;
    float* XT = ws + OFF_XT;

    ef_kernel<<<dim3(128, 2), 128, 0, stream>>>(M, E, F);
    solve_kernel<<<1, 256, 0, stream>>>(E, F, A);
    /* A^64 by repeated squaring: A2,A4,A8,A16,A32,A64 */
    matmul128_kernel<<<128, 128, 0, stream>>>(A,  A,  P0);
    matmul128_kernel<<<128, 128, 0, stream>>>(P0, P0, P1);
    matmul128_kernel<<<128, 128, 0, stream>>>(P1, P1, P0);
    matmul128_kernel<<<128, 128, 0, stream>>>(P0, P0, P1);
    matmul128_kernel<<<128, 128, 0, stream>>>(P1, P1, P0);
    matmul128_kernel<<<128, 128, 0, stream>>>(P0, P0, P1);
    phase1_kernel<<<NC * BATCH, 256, 0, stream>>>(u_, A, Bm, L);
    phase2_kernel<<<BATCH, 128, 0, stream>>>(P1, L, x0, Xc);

    size_t need = ((size_t)OFF_XT + XT_FLOATS) * sizeof(float);
    if (ws_size >= need) {
        phase3x_kernel<<<NC * BATCH, 256, 0, stream>>>(u_, A, Bm, Xc, XT);
        yemit_kernel<<<NC * BATCH, 256, 0, stream>>>(XT, C, y);
    } else {
        phase3_fb_kernel<<<NC * BATCH, 256, 0, stream>>>(u_, A, Bm, C, Xc, y);
    }
}